// Round 4
// baseline (59.141 us; speedup 1.0000x reference)
//
#include <hip/hip_runtime.h>
#include <cstddef>

#define B_ 32
#define N_ 128
#define D_ 128
#define NEG_SLOPE 0.01f

typedef float v4f __attribute__((ext_vector_type(4)));

// One block per (b,i), 256 threads.
// Phase 1 (hot): pure value stream — value[b,i,j,d] = e[b,i,d]*e[b,j,d],
//   nontemporal v4f stores, no cross-lane ops, fully unrolled.
// Phase 2 (cheap): scores via h = ei*w staged in LDS, dot with ej rows
//   (L1/L2-resident), leakyrelu, softmax over j, write alphas.
__global__ void __launch_bounds__(256)
fused_value_attn_kernel(const float* __restrict__ e,
                        const float* __restrict__ w,
                        const float* __restrict__ bias,
                        float* __restrict__ alphas,
                        float* __restrict__ value) {
    const int bi = blockIdx.x;          // b*N + i
    const int b  = bi >> 7;
    const int t  = threadIdx.x;
    const int d4 = t & 31;              // v4f index within D=128 row
    const int jg = t >> 5;              // 0..7

    __shared__ float h[D_];             // ei * w
    __shared__ float ph[256];           // per-thread partial dots
    __shared__ float red[N_];

    const v4f* __restrict__ e4 = reinterpret_cast<const v4f*>(e);
    const v4f ei4 = e4[(size_t)bi * 32 + d4];

    v4f* __restrict__ vout = reinterpret_cast<v4f*>(
        value + (size_t)bi * N_ * D_);

    // ---- Phase 1: streaming value writes (the 256 MB) ----
#pragma unroll
    for (int jj = 0; jj < 16; ++jj) {
        const int j = (jj << 3) + jg;   // 0..127
        const v4f ej4 = e4[((size_t)((b << 7) | j)) * 32 + d4];
        const v4f v4 = ei4 * ej4;
        __builtin_nontemporal_store(v4, &vout[(j << 5) + d4]);
    }

    // ---- Phase 2: scores + softmax (tiny, cache-resident) ----
    if (t < N_) h[t] = e[(size_t)bi * D_ + t] * w[t];
    __syncthreads();

    // 256 threads: j = t&127, half = t>>7 covers d in [half*64, half*64+64)
    const int j2   = t & 127;
    const int half = t >> 7;
    const float* __restrict__ ejrow = e + ((size_t)((b << 7) | j2)) * D_ + (half << 6);
    const float* __restrict__ hrow  = h + (half << 6);
    float p = 0.f;
#pragma unroll
    for (int q = 0; q < 16; ++q) {
        const v4f ejv = *reinterpret_cast<const v4f*>(ejrow + (q << 2));
        const v4f hv  = *reinterpret_cast<const v4f*>(hrow + (q << 2));
        const v4f pr  = hv * ejv;
        p += pr.x + pr.y + pr.z + pr.w;
    }
    ph[t] = p;
    __syncthreads();

    float s = 0.f, ex = 0.f;
    if (t < N_) {
        s = ph[t] + ph[t + 128] + bias[0];
        s = (s >= 0.f) ? s : NEG_SLOPE * s;
        red[t] = s;
    }
    __syncthreads();
#pragma unroll
    for (int off = 64; off > 0; off >>= 1) {
        if (t < off) red[t] = fmaxf(red[t], red[t + off]);
        __syncthreads();
    }
    const float m = red[0];
    __syncthreads();
    if (t < N_) { ex = expf(s - m); red[t] = ex; }
    __syncthreads();
#pragma unroll
    for (int off = 64; off > 0; off >>= 1) {
        if (t < off) red[t] += red[t + off];
        __syncthreads();
    }
    if (t < N_) alphas[(size_t)bi * N_ + t] = ex / red[0];
}

extern "C" void kernel_launch(void* const* d_in, const int* in_sizes, int n_in,
                              void* d_out, int out_size, void* d_ws, size_t ws_size,
                              hipStream_t stream) {
    const float* e    = (const float*)d_in[0];   // [B, N, D]
    const float* w    = (const float*)d_in[1];   // [D]
    const float* bias = (const float*)d_in[2];   // [1]

    float* out    = (float*)d_out;
    float* alphas = out;                              // B*N*N
    float* value  = out + (size_t)B_ * N_ * N_;       // B*N*N*D

    fused_value_attn_kernel<<<B_ * N_, 256, 0, stream>>>(e, w, bias, alphas, value);
}